// Round 1
// baseline (82.746 us; speedup 1.0000x reference)
//
#include <hip/hip_runtime.h>
#include <math.h>

// Problem geometry (fixed by the reference): B=32, C=1, H=W=1024.
#define NB 32
#define PER_BATCH (1024 * 1024)          // elements per batch row (C*H*W)
#define BLOCKS_PER_BATCH 64
#define THREADS 256
#define ELEMS_PER_BLOCK (PER_BATCH / BLOCKS_PER_BATCH)   // 16384
#define V4_PER_BLOCK (ELEMS_PER_BLOCK / 4)               // 4096
#define V4_PER_THREAD (V4_PER_BLOCK / THREADS)           // 16

// Workspace layout (floats): [0] = bce sum (global)
//                            [1 .. 32]  = per-batch sum(p)
//                            [33 .. 64] = per-batch sum(p*t)
//                            [65 .. 96] = per-batch sum(t)
#define WS_FLOATS (1 + 3 * NB)

__global__ __launch_bounds__(THREADS) void
loss_pass1(const float4* __restrict__ x4, const float4* __restrict__ t4,
           float* __restrict__ acc) {
    const int blk = blockIdx.x;
    const int batch = blk / BLOCKS_PER_BATCH;
    const int bblk = blk % BLOCKS_PER_BATCH;
    const size_t base = (size_t)batch * (PER_BATCH / 4) + (size_t)bblk * V4_PER_BLOCK;

    float bce = 0.f, ps = 0.f, pts = 0.f, ts = 0.f;

#pragma unroll
    for (int k = 0; k < V4_PER_THREAD; ++k) {
        const float4 xv = x4[base + threadIdx.x + (size_t)k * THREADS];
        const float4 tv = t4[base + threadIdx.x + (size_t)k * THREADS];
#pragma unroll
        for (int j = 0; j < 4; ++j) {
            const float x = ((const float*)&xv)[j];
            const float t = ((const float*)&tv)[j];
            const float ax = fabsf(x);
            const float e = __expf(-ax);          // exp(-|x|) in (0,1]
            const float inv = 1.0f / (1.0f + e);
            const float p = (x >= 0.f) ? inv : e * inv;   // sigmoid(x)
            // bce term: max(x,0) - x*t + log1p(exp(-|x|))
            bce += fmaxf(x, 0.f) - x * t + __logf(1.0f + e);
            ps += p;
            pts += p * t;
            ts += t;
        }
    }

    // Wave (64-lane) butterfly reduce of the 4 partials.
    for (int off = 32; off > 0; off >>= 1) {
        bce += __shfl_down(bce, off);
        ps  += __shfl_down(ps, off);
        pts += __shfl_down(pts, off);
        ts  += __shfl_down(ts, off);
    }

    __shared__ float red[4][4];   // [wave][value]
    const int lane = threadIdx.x & 63;
    const int wave = threadIdx.x >> 6;
    if (lane == 0) {
        red[wave][0] = bce; red[wave][1] = ps;
        red[wave][2] = pts; red[wave][3] = ts;
    }
    __syncthreads();
    if (threadIdx.x == 0) {
        for (int w = 1; w < 4; ++w) {
            bce += red[w][0]; ps += red[w][1];
            pts += red[w][2]; ts += red[w][3];
        }
        atomicAdd(&acc[0], bce);
        atomicAdd(&acc[1 + batch], ps);
        atomicAdd(&acc[1 + NB + batch], pts);
        atomicAdd(&acc[1 + 2 * NB + batch], ts);
    }
}

__global__ void loss_final(const float* __restrict__ acc, float* __restrict__ out) {
    const int i = threadIdx.x;   // 64 threads, one batch per lane for i < 32
    float coef = 0.f;
    if (i < NB) {
        const float ps  = acc[1 + i];
        const float pts = acc[1 + NB + i];
        const float ts  = acc[1 + 2 * NB + i];
        coef = (2.0f * pts + 1e-5f) / (ps + ts + 1e-5f);
    }
    for (int off = 32; off > 0; off >>= 1) coef += __shfl_down(coef, off);
    if (i == 0) {
        const double n = (double)NB * (double)PER_BATCH;
        const float bce = (float)((double)acc[0] / n);
        // csd_loss is identically 0 (dt_map is zeros_like).
        out[0] = bce + 1.0f - coef / (float)NB;
    }
}

extern "C" void kernel_launch(void* const* d_in, const int* in_sizes, int n_in,
                              void* d_out, int out_size, void* d_ws, size_t ws_size,
                              hipStream_t stream) {
    const float4* x4 = (const float4*)d_in[0];
    const float4* t4 = (const float4*)d_in[1];
    float* acc = (float*)d_ws;
    float* out = (float*)d_out;

    hipMemsetAsync(acc, 0, WS_FLOATS * sizeof(float), stream);

    const int grid = NB * BLOCKS_PER_BATCH;   // 2048 blocks
    loss_pass1<<<grid, THREADS, 0, stream>>>(x4, t4, acc);
    loss_final<<<1, 64, 0, stream>>>(acc, out);
}

// Round 2
// 79.604 us; speedup vs baseline: 1.0395x; 1.0395x over previous
//
#include <hip/hip_runtime.h>
#include <math.h>

// Problem geometry (fixed by the reference): B=32, C=1, H=W=1024.
#define NB 32
#define PER_BATCH (1024 * 1024)          // elements per batch row (C*H*W)
#define BLOCKS_PER_BATCH 64
#define THREADS 256
#define ELEMS_PER_BLOCK (PER_BATCH / BLOCKS_PER_BATCH)   // 16384
#define V4_PER_BLOCK (ELEMS_PER_BLOCK / 4)               // 4096
#define V4_PER_THREAD (V4_PER_BLOCK / THREADS)           // 16
#define BATCH4 4                                          // float4-pairs in flight

// Workspace layout (floats): [0] = bce sum (global)
//                            [1 .. 32]  = per-batch sum(p)
//                            [33 .. 64] = per-batch sum(p*t)
//                            [65 .. 96] = per-batch sum(t)
#define WS_FLOATS (1 + 3 * NB)

__global__ __launch_bounds__(THREADS) void
loss_pass1(const float4* __restrict__ x4, const float4* __restrict__ t4,
           float* __restrict__ acc) {
    const int blk = blockIdx.x;
    const int batch = blk / BLOCKS_PER_BATCH;
    const int bblk = blk % BLOCKS_PER_BATCH;
    const size_t base = (size_t)batch * (PER_BATCH / 4) + (size_t)bblk * V4_PER_BLOCK
                        + threadIdx.x;

    // Dual accumulators to shorten the serial add chains.
    float bce0 = 0.f, bce1 = 0.f;
    float ps0 = 0.f, ps1 = 0.f;
    float pts0 = 0.f, pts1 = 0.f;
    float ts0 = 0.f, ts1 = 0.f;

#pragma unroll
    for (int k = 0; k < V4_PER_THREAD; k += BATCH4) {
        float4 xv[BATCH4], tv[BATCH4];
        // Issue all 8 loads before any compute -> 8 outstanding vmem ops/thread.
#pragma unroll
        for (int u = 0; u < BATCH4; ++u) {
            xv[u] = x4[base + (size_t)(k + u) * THREADS];
            tv[u] = t4[base + (size_t)(k + u) * THREADS];
        }
#pragma unroll
        for (int u = 0; u < BATCH4; ++u) {
#pragma unroll
            for (int j = 0; j < 4; ++j) {
                const float x = ((const float*)&xv[u])[j];
                const float t = ((const float*)&tv[u])[j];
                const float ax = fabsf(x);
                const float e = __expf(-ax);                 // exp(-|x|) in (0,1]
                const float ope = 1.0f + e;
                const float inv = __builtin_amdgcn_rcpf(ope); // ~1ulp v_rcp_f32
                const float p = (x >= 0.f) ? inv : e * inv;   // sigmoid(x)
                const float lg = __logf(ope);                 // log1p(exp(-|x|))
                if (j & 1) {
                    bce1 += fmaxf(x, 0.f) + lg - x * t;
                    ps1 += p;
                    pts1 = __builtin_fmaf(p, t, pts1);
                    ts1 += t;
                } else {
                    bce0 += fmaxf(x, 0.f) + lg - x * t;
                    ps0 += p;
                    pts0 = __builtin_fmaf(p, t, pts0);
                    ts0 += t;
                }
            }
        }
    }

    float bce = bce0 + bce1;
    float ps = ps0 + ps1;
    float pts = pts0 + pts1;
    float ts = ts0 + ts1;

    // Wave (64-lane) butterfly reduce of the 4 partials.
    for (int off = 32; off > 0; off >>= 1) {
        bce += __shfl_down(bce, off);
        ps  += __shfl_down(ps, off);
        pts += __shfl_down(pts, off);
        ts  += __shfl_down(ts, off);
    }

    __shared__ float red[4][4];   // [wave][value]
    const int lane = threadIdx.x & 63;
    const int wave = threadIdx.x >> 6;
    if (lane == 0) {
        red[wave][0] = bce; red[wave][1] = ps;
        red[wave][2] = pts; red[wave][3] = ts;
    }
    __syncthreads();
    if (threadIdx.x == 0) {
        for (int w = 1; w < 4; ++w) {
            bce += red[w][0]; ps += red[w][1];
            pts += red[w][2]; ts += red[w][3];
        }
        atomicAdd(&acc[0], bce);
        atomicAdd(&acc[1 + batch], ps);
        atomicAdd(&acc[1 + NB + batch], pts);
        atomicAdd(&acc[1 + 2 * NB + batch], ts);
    }
}

__global__ void loss_final(const float* __restrict__ acc, float* __restrict__ out) {
    const int i = threadIdx.x;   // 64 threads, one batch per lane for i < 32
    float coef = 0.f;
    if (i < NB) {
        const float ps  = acc[1 + i];
        const float pts = acc[1 + NB + i];
        const float ts  = acc[1 + 2 * NB + i];
        coef = (2.0f * pts + 1e-5f) / (ps + ts + 1e-5f);
    }
    for (int off = 32; off > 0; off >>= 1) coef += __shfl_down(coef, off);
    if (i == 0) {
        const double n = (double)NB * (double)PER_BATCH;
        const float bce = (float)((double)acc[0] / n);
        // csd_loss is identically 0 (dt_map is zeros_like).
        out[0] = bce + 1.0f - coef / (float)NB;
    }
}

extern "C" void kernel_launch(void* const* d_in, const int* in_sizes, int n_in,
                              void* d_out, int out_size, void* d_ws, size_t ws_size,
                              hipStream_t stream) {
    const float4* x4 = (const float4*)d_in[0];
    const float4* t4 = (const float4*)d_in[1];
    float* acc = (float*)d_ws;
    float* out = (float*)d_out;

    hipMemsetAsync(acc, 0, WS_FLOATS * sizeof(float), stream);

    const int grid = NB * BLOCKS_PER_BATCH;   // 2048 blocks
    loss_pass1<<<grid, THREADS, 0, stream>>>(x4, t4, acc);
    loss_final<<<1, 64, 0, stream>>>(acc, out);
}

// Round 3
// 56.797 us; speedup vs baseline: 1.4569x; 1.4015x over previous
//
#include <hip/hip_runtime.h>
#include <math.h>

// Problem geometry (fixed by the reference): B=32, C=1, H=W=1024.
#define NB 32
#define PER_BATCH (1024 * 1024)          // elements per batch row (C*H*W)
#define BLOCKS_PER_BATCH 64
#define THREADS 256
#define NBLOCKS (NB * BLOCKS_PER_BATCH)                  // 2048
#define ELEMS_PER_BLOCK (PER_BATCH / BLOCKS_PER_BATCH)   // 16384
#define V4_PER_BLOCK (ELEMS_PER_BLOCK / 4)               // 4096
#define V4_PER_THREAD (V4_PER_BLOCK / THREADS)           // 16
// 8 batches of 2 float4-pairs each; 3 rotating register buffers.
#define BW 2

// ws layout: float4 partials[NBLOCKS]  = {bce, ps, pts, ts} per block.

#define LOADB(XB, TB, K)                                           \
    XB[0] = x4[base + (size_t)((K) * BW + 0) * THREADS];           \
    XB[1] = x4[base + (size_t)((K) * BW + 1) * THREADS];           \
    TB[0] = t4[base + (size_t)((K) * BW + 0) * THREADS];           \
    TB[1] = t4[base + (size_t)((K) * BW + 1) * THREADS];

#define COMPB(XB, TB)                                              \
    _Pragma("unroll")                                              \
    for (int u = 0; u < BW; ++u) {                                 \
        _Pragma("unroll")                                          \
        for (int j = 0; j < 4; ++j) {                              \
            const float x = ((const float*)&XB[u])[j];             \
            const float t = ((const float*)&TB[u])[j];             \
            const float e = __expf(-fabsf(x));                     \
            const float ope = 1.0f + e;                            \
            const float inv = __builtin_amdgcn_rcpf(ope);          \
            const float p = (x >= 0.f) ? inv : e * inv;            \
            const float lg = __logf(ope);                          \
            if (j & 1) {                                           \
                bce1 += fmaxf(x, 0.f) + lg - x * t;                \
                ps1 += p;                                          \
                pts1 = __builtin_fmaf(p, t, pts1);                 \
                ts1 += t;                                          \
            } else {                                               \
                bce0 += fmaxf(x, 0.f) + lg - x * t;                \
                ps0 += p;                                          \
                pts0 = __builtin_fmaf(p, t, pts0);                 \
                ts0 += t;                                          \
            }                                                      \
        }                                                          \
    }

__global__ __launch_bounds__(THREADS) void
loss_pass1(const float4* __restrict__ x4, const float4* __restrict__ t4,
           float4* __restrict__ partials) {
    const int blk = blockIdx.x;
    const int batch = blk / BLOCKS_PER_BATCH;
    const int bblk = blk % BLOCKS_PER_BATCH;
    const size_t base = (size_t)batch * (PER_BATCH / 4) + (size_t)bblk * V4_PER_BLOCK
                        + threadIdx.x;

    float bce0 = 0.f, bce1 = 0.f;
    float ps0 = 0.f, ps1 = 0.f;
    float pts0 = 0.f, pts1 = 0.f;
    float ts0 = 0.f, ts1 = 0.f;

    // 3-deep rotating register pipeline over 8 batches: loads of batch k+2
    // are in flight while batch k computes.
    float4 xa[BW], ta[BW], xb[BW], tb[BW], xc[BW], tc[BW];
    LOADB(xa, ta, 0)
    LOADB(xb, tb, 1)
    LOADB(xc, tc, 2)
    COMPB(xa, ta)  LOADB(xa, ta, 3)
    COMPB(xb, tb)  LOADB(xb, tb, 4)
    COMPB(xc, tc)  LOADB(xc, tc, 5)
    COMPB(xa, ta)  LOADB(xa, ta, 6)
    COMPB(xb, tb)  LOADB(xb, tb, 7)
    COMPB(xc, tc)
    COMPB(xa, ta)
    COMPB(xb, tb)

    float bce = bce0 + bce1;
    float ps = ps0 + ps1;
    float pts = pts0 + pts1;
    float ts = ts0 + ts1;

    // Wave (64-lane) butterfly reduce of the 4 partials.
    for (int off = 32; off > 0; off >>= 1) {
        bce += __shfl_down(bce, off);
        ps  += __shfl_down(ps, off);
        pts += __shfl_down(pts, off);
        ts  += __shfl_down(ts, off);
    }

    __shared__ float red[4][4];   // [wave][value]
    const int lane = threadIdx.x & 63;
    const int wave = threadIdx.x >> 6;
    if (lane == 0) {
        red[wave][0] = bce; red[wave][1] = ps;
        red[wave][2] = pts; red[wave][3] = ts;
    }
    __syncthreads();
    if (threadIdx.x == 0) {
        for (int w = 1; w < 4; ++w) {
            bce += red[w][0]; ps += red[w][1];
            pts += red[w][2]; ts += red[w][3];
        }
        partials[blk] = make_float4(bce, ps, pts, ts);  // no atomics
    }
}

__global__ __launch_bounds__(1024) void
loss_final(const float4* __restrict__ partials, float* __restrict__ out) {
    __shared__ float sps[NB], spts[NB], sts[NB];
    __shared__ float sbce[16];
    const int i = threadIdx.x;          // 1024 threads = 16 waves
    const int lane = i & 63;
    const int wave = i >> 6;

    if (i < NB) { sps[i] = 0.f; spts[i] = 0.f; sts[i] = 0.f; }
    __syncthreads();

    const float4 a = partials[i];
    const float4 b = partials[i + 1024];
    float bce = a.x + b.x;
    const int batchA = i >> 6;            // blocks 0..1023   -> batches 0..15
    const int batchB = (i + 1024) >> 6;   // blocks 1024..2047 -> batches 16..31
    atomicAdd(&sps[batchA], a.y); atomicAdd(&spts[batchA], a.z); atomicAdd(&sts[batchA], a.w);
    atomicAdd(&sps[batchB], b.y); atomicAdd(&spts[batchB], b.z); atomicAdd(&sts[batchB], b.w);

    for (int off = 32; off > 0; off >>= 1) bce += __shfl_down(bce, off);
    if (lane == 0) sbce[wave] = bce;
    __syncthreads();

    if (i < 64) {
        float coef = 0.f;
        if (i < NB) coef = (2.0f * spts[i] + 1e-5f) / (sps[i] + sts[i] + 1e-5f);
        for (int off = 32; off > 0; off >>= 1) coef += __shfl_down(coef, off);
        if (i == 0) {
            float bt = 0.f;
            for (int w = 0; w < 16; ++w) bt += sbce[w];
            const double n = (double)NB * (double)PER_BATCH;
            // csd_loss is identically 0 (dt_map is zeros_like).
            out[0] = (float)((double)bt / n) + 1.0f - coef / (float)NB;
        }
    }
}

extern "C" void kernel_launch(void* const* d_in, const int* in_sizes, int n_in,
                              void* d_out, int out_size, void* d_ws, size_t ws_size,
                              hipStream_t stream) {
    const float4* x4 = (const float4*)d_in[0];
    const float4* t4 = (const float4*)d_in[1];
    float4* partials = (float4*)d_ws;     // NBLOCKS float4 = 32 KB, fully
    float* out = (float*)d_out;           // rewritten every launch

    loss_pass1<<<NBLOCKS, THREADS, 0, stream>>>(x4, t4, partials);
    loss_final<<<1, 1024, 0, stream>>>(partials, out);
}

// Round 4
// 56.663 us; speedup vs baseline: 1.4603x; 1.0024x over previous
//
#include <hip/hip_runtime.h>
#include <math.h>

// Problem geometry (fixed by the reference): B=32, C=1, H=W=1024.
#define NB 32
#define PER_BATCH (1024 * 1024)          // elements per batch row (C*H*W)
#define BLOCKS_PER_BATCH 64
#define THREADS 256
#define NBLOCKS (NB * BLOCKS_PER_BATCH)                  // 2048
#define ELEMS_PER_BLOCK (PER_BATCH / BLOCKS_PER_BATCH)   // 16384
#define V4_PER_BLOCK (ELEMS_PER_BLOCK / 4)               // 4096
#define V4_PER_THREAD (V4_PER_BLOCK / THREADS)           // 16 batches of 1 pair

// ws layout: float4 partials[NBLOCKS] = {bce, ps, pts, ts} per block.

#define SB __builtin_amdgcn_sched_barrier(0);

#define LOAD1(XB, TB, K)                                  \
    XB = x4[base + (size_t)(K) * THREADS];                \
    TB = t4[base + (size_t)(K) * THREADS];

#define COMP1(XB, TB)                                              \
    _Pragma("unroll")                                              \
    for (int j = 0; j < 4; ++j) {                                  \
        const float x = ((const float*)&XB)[j];                    \
        const float t = ((const float*)&TB)[j];                    \
        const float e = __expf(-fabsf(x));                         \
        const float ope = 1.0f + e;                                \
        const float inv = __builtin_amdgcn_rcpf(ope);              \
        const float p = (x >= 0.f) ? inv : e * inv;                \
        const float lg = __logf(ope);                              \
        if (j & 1) {                                               \
            bce1 += __builtin_fmaf(-x, t, fmaxf(x, 0.f) + lg);     \
            ps1 += p;                                              \
            pts1 = __builtin_fmaf(p, t, pts1);                     \
            ts1 += t;                                              \
        } else {                                                   \
            bce0 += __builtin_fmaf(-x, t, fmaxf(x, 0.f) + lg);     \
            ps0 += p;                                              \
            pts0 = __builtin_fmaf(p, t, pts0);                     \
            ts0 += t;                                              \
        }                                                          \
    }

__global__ __launch_bounds__(THREADS) void
loss_pass1(const float4* __restrict__ x4, const float4* __restrict__ t4,
           float4* __restrict__ partials) {
    const int blk = blockIdx.x;
    const int batch = blk / BLOCKS_PER_BATCH;
    const int bblk = blk % BLOCKS_PER_BATCH;
    const size_t base = (size_t)batch * (PER_BATCH / 4) + (size_t)bblk * V4_PER_BLOCK
                        + threadIdx.x;

    float bce0 = 0.f, bce1 = 0.f;
    float ps0 = 0.f, ps1 = 0.f;
    float pts0 = 0.f, pts1 = 0.f;
    float ts0 = 0.f, ts1 = 0.f;

    // 4-deep rotating register pipeline over 16 one-float4-pair batches.
    // sched_barrier(0) fences pin the issue order so the compiler cannot
    // collapse the buffers: loads of batch k+4 stay in flight across the
    // compute of batch k (~8 outstanding 16B loads/thread).
    float4 xa, ta, xb, tb, xc, tc, xd, td;
    LOAD1(xa, ta, 0)
    LOAD1(xb, tb, 1)
    LOAD1(xc, tc, 2)
    LOAD1(xd, td, 3)
    SB
    COMP1(xa, ta)  LOAD1(xa, ta, 4)   SB
    COMP1(xb, tb)  LOAD1(xb, tb, 5)   SB
    COMP1(xc, tc)  LOAD1(xc, tc, 6)   SB
    COMP1(xd, td)  LOAD1(xd, td, 7)   SB
    COMP1(xa, ta)  LOAD1(xa, ta, 8)   SB
    COMP1(xb, tb)  LOAD1(xb, tb, 9)   SB
    COMP1(xc, tc)  LOAD1(xc, tc, 10)  SB
    COMP1(xd, td)  LOAD1(xd, td, 11)  SB
    COMP1(xa, ta)  LOAD1(xa, ta, 12)  SB
    COMP1(xb, tb)  LOAD1(xb, tb, 13)  SB
    COMP1(xc, tc)  LOAD1(xc, tc, 14)  SB
    COMP1(xd, td)  LOAD1(xd, td, 15)  SB
    COMP1(xa, ta)
    COMP1(xb, tb)
    COMP1(xc, tc)
    COMP1(xd, td)

    float bce = bce0 + bce1;
    float ps = ps0 + ps1;
    float pts = pts0 + pts1;
    float ts = ts0 + ts1;

    // Wave (64-lane) butterfly reduce of the 4 partials.
    for (int off = 32; off > 0; off >>= 1) {
        bce += __shfl_down(bce, off);
        ps  += __shfl_down(ps, off);
        pts += __shfl_down(pts, off);
        ts  += __shfl_down(ts, off);
    }

    __shared__ float red[4][4];   // [wave][value]
    const int lane = threadIdx.x & 63;
    const int wave = threadIdx.x >> 6;
    if (lane == 0) {
        red[wave][0] = bce; red[wave][1] = ps;
        red[wave][2] = pts; red[wave][3] = ts;
    }
    __syncthreads();
    if (threadIdx.x == 0) {
        for (int w = 1; w < 4; ++w) {
            bce += red[w][0]; ps += red[w][1];
            pts += red[w][2]; ts += red[w][3];
        }
        partials[blk] = make_float4(bce, ps, pts, ts);  // no atomics
    }
}

__global__ __launch_bounds__(1024) void
loss_final(const float4* __restrict__ partials, float* __restrict__ out) {
    __shared__ float sps[NB], spts[NB], sts[NB];
    __shared__ float sbce[16];
    const int i = threadIdx.x;          // 1024 threads = 16 waves
    const int lane = i & 63;
    const int wave = i >> 6;

    if (i < NB) { sps[i] = 0.f; spts[i] = 0.f; sts[i] = 0.f; }
    __syncthreads();

    const float4 a = partials[i];
    const float4 b = partials[i + 1024];
    float bce = a.x + b.x;
    const int batchA = i >> 6;            // blocks 0..1023    -> batches 0..15
    const int batchB = (i + 1024) >> 6;   // blocks 1024..2047 -> batches 16..31
    atomicAdd(&sps[batchA], a.y); atomicAdd(&spts[batchA], a.z); atomicAdd(&sts[batchA], a.w);
    atomicAdd(&sps[batchB], b.y); atomicAdd(&spts[batchB], b.z); atomicAdd(&sts[batchB], b.w);

    for (int off = 32; off > 0; off >>= 1) bce += __shfl_down(bce, off);
    if (lane == 0) sbce[wave] = bce;
    __syncthreads();

    if (i < 64) {
        float coef = 0.f;
        if (i < NB) coef = (2.0f * spts[i] + 1e-5f) / (sps[i] + sts[i] + 1e-5f);
        for (int off = 32; off > 0; off >>= 1) coef += __shfl_down(coef, off);
        if (i == 0) {
            float bt = 0.f;
            for (int w = 0; w < 16; ++w) bt += sbce[w];
            const double n = (double)NB * (double)PER_BATCH;
            // csd_loss is identically 0 (dt_map is zeros_like).
            out[0] = (float)((double)bt / n) + 1.0f - coef / (float)NB;
        }
    }
}

extern "C" void kernel_launch(void* const* d_in, const int* in_sizes, int n_in,
                              void* d_out, int out_size, void* d_ws, size_t ws_size,
                              hipStream_t stream) {
    const float4* x4 = (const float4*)d_in[0];
    const float4* t4 = (const float4*)d_in[1];
    float4* partials = (float4*)d_ws;     // NBLOCKS float4 = 32 KB, fully
    float* out = (float*)d_out;           // rewritten every launch

    loss_pass1<<<NBLOCKS, THREADS, 0, stream>>>(x4, t4, partials);
    loss_final<<<1, 1024, 0, stream>>>(partials, out);
}

// Round 5
// 56.368 us; speedup vs baseline: 1.4680x; 1.0052x over previous
//
#include <hip/hip_runtime.h>
#include <math.h>

// Problem geometry (fixed by the reference): B=32, C=1, H=W=1024.
#define NB 32
#define PER_BATCH (1024 * 1024)          // elements per batch row (C*H*W)
#define BLOCKS_PER_BATCH 64
#define THREADS 256
#define NBLOCKS (NB * BLOCKS_PER_BATCH)                  // 2048
#define ELEMS_PER_BLOCK (PER_BATCH / BLOCKS_PER_BATCH)   // 16384
#define V4_PER_BLOCK (ELEMS_PER_BLOCK / 4)               // 4096
#define V4_PER_THREAD (V4_PER_BLOCK / THREADS)           // 16 stages of 1 pair

typedef __attribute__((ext_vector_type(4))) float f32x4;

// ws layout: float4 partials[NBLOCKS] = {bce, ps, pts, ts} per block.

// Opaque asm loads: compiler cannot sink/collapse them, and inserts no
// vmcnt drains (it doesn't know they are loads). We count vmcnt by hand:
// depth-4 pipeline, 2 loads/stage -> steady-state wait is vmcnt(6).
#define LOADP(XB, TB, K)                                                      \
    {                                                                         \
        const uint32_t vo = base_off + (uint32_t)((K) * THREADS * 16);        \
        asm volatile("global_load_dwordx4 %0, %2, %3\n\t"                     \
                     "global_load_dwordx4 %1, %2, %4"                         \
                     : "=&v"(XB), "=&v"(TB)                                   \
                     : "v"(vo), "s"(x4), "s"(t4));                            \
    }

#define WAITV(N)                                                              \
    asm volatile("s_waitcnt vmcnt(" #N ")" ::: "memory");                     \
    __builtin_amdgcn_sched_barrier(0);

#define COMP1(XB, TB)                                              \
    _Pragma("unroll")                                              \
    for (int j = 0; j < 4; ++j) {                                  \
        const float x = XB[j];                                     \
        const float t = TB[j];                                     \
        const float e = __expf(-fabsf(x));                         \
        const float ope = 1.0f + e;                                \
        const float inv = __builtin_amdgcn_rcpf(ope);              \
        const float p = (x >= 0.f) ? inv : 1.0f - inv;             \
        const float lg = __logf(ope);                              \
        if (j & 1) {                                               \
            bce1 += __builtin_fmaf(-x, t, fmaxf(x, 0.f) + lg);     \
            ps1 += p;                                              \
            pts1 = __builtin_fmaf(p, t, pts1);                     \
            ts1 += t;                                              \
        } else {                                                   \
            bce0 += __builtin_fmaf(-x, t, fmaxf(x, 0.f) + lg);     \
            ps0 += p;                                              \
            pts0 = __builtin_fmaf(p, t, pts0);                     \
            ts0 += t;                                              \
        }                                                          \
    }

__global__ __launch_bounds__(THREADS) void
loss_pass1(const float4* __restrict__ x4p, const float4* __restrict__ t4p,
           float4* __restrict__ partials) {
    const int blk = blockIdx.x;
    const int batch = blk / BLOCKS_PER_BATCH;
    const int bblk = blk % BLOCKS_PER_BATCH;
    const float* x4 = (const float*)x4p;   // SGPR base for asm loads
    const float* t4 = (const float*)t4p;
    const uint32_t base_off =
        (uint32_t)(((size_t)batch * (PER_BATCH / 4) +
                    (size_t)bblk * V4_PER_BLOCK + threadIdx.x) * 16u);

    float bce0 = 0.f, bce1 = 0.f;
    float ps0 = 0.f, ps1 = 0.f;
    float pts0 = 0.f, pts1 = 0.f;
    float ts0 = 0.f, ts1 = 0.f;

    f32x4 xa, ta, xb, tb, xc, tc, xd, td;
    // Prologue: fill the 4-deep pipeline (8 loads in flight).
    LOADP(xa, ta, 0)
    LOADP(xb, tb, 1)
    LOADP(xc, tc, 2)
    LOADP(xd, td, 3)
    // Steady state: wait only for the oldest pair, compute, refill.
    WAITV(6)  COMP1(xa, ta)  LOADP(xa, ta, 4)
    WAITV(6)  COMP1(xb, tb)  LOADP(xb, tb, 5)
    WAITV(6)  COMP1(xc, tc)  LOADP(xc, tc, 6)
    WAITV(6)  COMP1(xd, td)  LOADP(xd, td, 7)
    WAITV(6)  COMP1(xa, ta)  LOADP(xa, ta, 8)
    WAITV(6)  COMP1(xb, tb)  LOADP(xb, tb, 9)
    WAITV(6)  COMP1(xc, tc)  LOADP(xc, tc, 10)
    WAITV(6)  COMP1(xd, td)  LOADP(xd, td, 11)
    WAITV(6)  COMP1(xa, ta)  LOADP(xa, ta, 12)
    WAITV(6)  COMP1(xb, tb)  LOADP(xb, tb, 13)
    WAITV(6)  COMP1(xc, tc)  LOADP(xc, tc, 14)
    WAITV(6)  COMP1(xd, td)  LOADP(xd, td, 15)
    // Epilogue: drain 6 -> 4 -> 2 -> 0.
    WAITV(6)  COMP1(xa, ta)
    WAITV(4)  COMP1(xb, tb)
    WAITV(2)  COMP1(xc, tc)
    WAITV(0)  COMP1(xd, td)

    float bce = bce0 + bce1;
    float ps = ps0 + ps1;
    float pts = pts0 + pts1;
    float ts = ts0 + ts1;

    // Wave (64-lane) butterfly reduce of the 4 partials.
    for (int off = 32; off > 0; off >>= 1) {
        bce += __shfl_down(bce, off);
        ps  += __shfl_down(ps, off);
        pts += __shfl_down(pts, off);
        ts  += __shfl_down(ts, off);
    }

    __shared__ float red[4][4];   // [wave][value]
    const int lane = threadIdx.x & 63;
    const int wave = threadIdx.x >> 6;
    if (lane == 0) {
        red[wave][0] = bce; red[wave][1] = ps;
        red[wave][2] = pts; red[wave][3] = ts;
    }
    __syncthreads();
    if (threadIdx.x == 0) {
        for (int w = 1; w < 4; ++w) {
            bce += red[w][0]; ps += red[w][1];
            pts += red[w][2]; ts += red[w][3];
        }
        partials[blk] = make_float4(bce, ps, pts, ts);  // no atomics
    }
}

__global__ __launch_bounds__(1024) void
loss_final(const float4* __restrict__ partials, float* __restrict__ out) {
    __shared__ float sps[NB], spts[NB], sts[NB];
    __shared__ float sbce[16];
    const int i = threadIdx.x;          // 1024 threads = 16 waves
    const int lane = i & 63;
    const int wave = i >> 6;

    if (i < NB) { sps[i] = 0.f; spts[i] = 0.f; sts[i] = 0.f; }
    __syncthreads();

    const float4 a = partials[i];
    const float4 b = partials[i + 1024];
    float bce = a.x + b.x;
    const int batchA = i >> 6;            // blocks 0..1023    -> batches 0..15
    const int batchB = (i + 1024) >> 6;   // blocks 1024..2047 -> batches 16..31
    atomicAdd(&sps[batchA], a.y); atomicAdd(&spts[batchA], a.z); atomicAdd(&sts[batchA], a.w);
    atomicAdd(&sps[batchB], b.y); atomicAdd(&spts[batchB], b.z); atomicAdd(&sts[batchB], b.w);

    for (int off = 32; off > 0; off >>= 1) bce += __shfl_down(bce, off);
    if (lane == 0) sbce[wave] = bce;
    __syncthreads();

    if (i < 64) {
        float coef = 0.f;
        if (i < NB) coef = (2.0f * spts[i] + 1e-5f) / (sps[i] + sts[i] + 1e-5f);
        for (int off = 32; off > 0; off >>= 1) coef += __shfl_down(coef, off);
        if (i == 0) {
            float bt = 0.f;
            for (int w = 0; w < 16; ++w) bt += sbce[w];
            const double n = (double)NB * (double)PER_BATCH;
            // csd_loss is identically 0 (dt_map is zeros_like).
            out[0] = (float)((double)bt / n) + 1.0f - coef / (float)NB;
        }
    }
}

extern "C" void kernel_launch(void* const* d_in, const int* in_sizes, int n_in,
                              void* d_out, int out_size, void* d_ws, size_t ws_size,
                              hipStream_t stream) {
    const float4* x4 = (const float4*)d_in[0];
    const float4* t4 = (const float4*)d_in[1];
    float4* partials = (float4*)d_ws;     // NBLOCKS float4 = 32 KB, fully
    float* out = (float*)d_out;           // rewritten every launch

    loss_pass1<<<NBLOCKS, THREADS, 0, stream>>>(x4, t4, partials);
    loss_final<<<1, 1024, 0, stream>>>(partials, out);
}